// Round 12
// baseline (640.917 us; speedup 1.0000x reference)
//
#include <hip/hip_runtime.h>
#include <hip/hip_bf16.h>
#include <stdint.h>
#include <math.h>

typedef unsigned short u16;
typedef unsigned int u32;
typedef unsigned long long u64;
typedef __attribute__((ext_vector_type(8))) short short8;
typedef __attribute__((ext_vector_type(4))) float f32x4;

static constexpr int BDIM  = 1024;   // batch
static constexpr int D_IN  = 784;
static constexpr int D_H   = 1024;
static constexpr int D_OUT = 10;
static constexpr int TSTEPS = 100;
static constexpr int K0SEG = 800;    // 784 padded to 800 (25*32)
static constexpr int K0TOT = 2400;   // 3 segments: ihi*whi + ihi*wlo + ilo*whi
static constexpr int NELEM = 1024 * 1024;

#define AL 0.9f
#define BE 0.85f

// ---------- helpers ----------
__device__ __forceinline__ void gld16(const void* g, void* l) {
  __builtin_amdgcn_global_load_lds(
      (const __attribute__((address_space(1))) u32*)g,
      (__attribute__((address_space(3))) u32*)l, 16, 0, 0);
}
__device__ __forceinline__ u16 f2bf(float v) {
  __hip_bfloat16 h = __float2bfloat16(v);
  u16 r; __builtin_memcpy(&r, &h, 2); return r;
}
__device__ __forceinline__ float bf2f(u16 b) {
  __hip_bfloat16 h; __builtin_memcpy(&h, &b, 2); return __bfloat162float(h);
}

// LDS bank-derotation (round-5, verified: SQ_LDS_BANK_CONFLICT -> 0):
// store: LDS[r][p] holds global 16B-slot c = (p - (r>>1)) & 3 of row r.
// Invariant across 16-row strips (strip stride 16 -> (r>>1) stride 8 == 0 mod 4).
__device__ __forceinline__ int stg_rot(int l) { return (((l & 3) - (l >> 3)) & 3) << 3; }
__device__ __forceinline__ int rd_rot(int l) {
  return (((l >> 4) + ((l & 15) >> 1)) & 3) << 3;
}

// ---------- prep: build bf16 hi/lo operand matrices ----------
__global__ void prep0(const float* __restrict__ inp, const float* __restrict__ W0,
                      u16* __restrict__ A0, u16* __restrict__ BT0) {
  int kp = blockIdx.x * 256 + threadIdx.x;
  if (kp >= K0TOT) return;
  int row = blockIdx.y;
  int seg = kp / K0SEG;
  int kk  = kp - seg * K0SEG;
  float av = (kk < D_IN) ? inp[row * D_IN + kk] : 0.f;
  u16 ahi = f2bf(av);
  u16 alo = f2bf(av - bf2f(ahi));
  A0[(size_t)row * K0TOT + kp] = (seg < 2) ? ahi : alo;
  float wv = (kk < D_IN) ? W0[kk * D_H + row] : 0.f;
  u16 whi = f2bf(wv);
  u16 wlo = f2bf(wv - bf2f(whi));
  BT0[(size_t)row * K0TOT + kp] = (seg == 0) ? whi : ((seg == 1) ? wlo : whi);
}

// W1s [n][2048]: k<1024 -> hi(W1[k][n]); k>=1024 -> lo residual (stacked-K)
__global__ void prep1s(const float* __restrict__ W1, u16* __restrict__ W1s) {
  int k = blockIdx.x * 256 + threadIdx.x;   // 0..2047
  int n = blockIdx.y;
  float v = W1[(size_t)(k & 1023) * D_H + n];
  u16 hi = f2bf(v);
  W1s[(size_t)n * 2048 + k] = (k < 1024) ? hi : f2bf(v - bf2f(hi));
}

// ---------- H0 GEMM (one-time): C[1024][1024] = A[1024][KTOT] * BT^T ----------
template <int KTOT>
__global__ __launch_bounds__(256) void gemm_bt_t(
    const u16* __restrict__ A, const u16* __restrict__ BT, float* __restrict__ C) {
  constexpr int N = 1024, NBN = 8;
  __shared__ u16 As[128 * 32];
  __shared__ u16 Bs[128 * 32];
  const int nwg = gridDim.x;
  const int bid = blockIdx.x;
  const int wg = (bid & 7) * (nwg >> 3) + (bid >> 3);
  const int bm = wg / NBN, bn = wg - bm * NBN;
  const int tid = threadIdx.x;
  const int w = tid >> 6, l = tid & 63;
  const int wm = w & 1, wn = w >> 1;
  const int srow = l >> 2;
  const int scol = stg_rot(l);
  const size_t m0 = (size_t)bm * 128, n0 = (size_t)bn * 128;
  const int r0 = w * 32;

  const u16* aP0 = &A[(m0 + r0 + srow) * KTOT + scol];
  const u16* aP1 = &A[(m0 + r0 + 16 + srow) * KTOT + scol];
  const u16* bP0 = &BT[(n0 + r0 + srow) * KTOT + scol];
  const u16* bP1 = &BT[(n0 + r0 + 16 + srow) * KTOT + scol];

  const int ps = rd_rot(l);

  f32x4 acc[4][4] = {};

  for (int kt = 0; kt < KTOT; kt += 32) {
    __syncthreads();
    gld16(aP0 + kt, &As[(r0) * 32]);
    gld16(aP1 + kt, &As[(r0 + 16) * 32]);
    gld16(bP0 + kt, &Bs[(r0) * 32]);
    gld16(bP1 + kt, &Bs[(r0 + 16) * 32]);
    __syncthreads();

    short8 a[4], b[4];
#pragma unroll
    for (int m = 0; m < 4; m++)
      a[m] = *(const short8*)&As[(wm * 64 + m * 16 + (l & 15)) * 32 + ps];
#pragma unroll
    for (int n = 0; n < 4; n++)
      b[n] = *(const short8*)&Bs[(wn * 64 + n * 16 + (l & 15)) * 32 + ps];
#pragma unroll
    for (int m = 0; m < 4; m++)
#pragma unroll
      for (int n = 0; n < 4; n++)
        acc[m][n] = __builtin_amdgcn_mfma_f32_16x16x32_bf16(a[m], b[n], acc[m][n], 0, 0, 0);
  }

  const int rr = (l >> 4) * 4, cc = l & 15;
#pragma unroll
  for (int m = 0; m < 4; m++)
#pragma unroll
    for (int n = 0; n < 4; n++) {
      size_t row = m0 + wm * 64 + m * 16 + rr;
      size_t col = n0 + wn * 64 + n * 16 + cc;
#pragma unroll
      for (int j = 0; j < 4; j++)
        C[(row + j) * (size_t)N + col] = acc[m][n][j];
    }
}

// ---------- layer-1 GEMM v5: 256x128 block, phase-interleaved, stacked-K ------
// C[M][1024] = A[M][1024(wrap)] @ W1s[1024][2048]^T-ish (stacked hi;lo).
// 4 waves (2Mx2N) of 128x64, acc[8][4]. BK=32, NT=64 K-steps.
// LDS 3buf x (A 256x32 + B 128x32) = 72KB -> 2 blocks/CU (dual2's footprint).
// Per K-step TWO phases, each {4-8 ds_read || 3 stage-gld; bar; 16 MFMA; bar}
// -> MFMA pipe fed while reads/stages issue (m196/m201 interleave essence).
// Counted vmcnt(6) once per step at Ph1 (FIFO: leaves exactly stage(t+2)'s 6
// outstanding => stage(t+1) landed before step t+1 reads). Derotation verbatim.
__global__ __launch_bounds__(256, 2) void gemm_dual5(
    const u16* __restrict__ A, const u16* __restrict__ Bs2, float* __restrict__ C) {
  constexpr int N = 1024, KA = 1024, KS = 2048, NT = 64;
  __shared__ u16 lds[3 * 12288];                 // buf: A(8192 u16) | B(4096 u16)
  const int nwg = gridDim.x;
  const int bid = blockIdx.x;
  const int wg = (bid & 7) * (nwg >> 3) + (bid >> 3);   // bijective: nwg % 8 == 0
  const int bm = wg >> 3, bn = wg & 7;           // N/128 = 8 column-blocks
  const int tid = threadIdx.x;
  const int w = tid >> 6, l = tid & 63;
  const int wm = w >> 1, wn = w & 1;             // 2x2 waves, per-wave 128x64
  const size_t m0 = (size_t)bm * 256, n0 = (size_t)bn * 128;

  const int srow = l >> 2;                       // staging: 16 rows x 64B per issue
  const int scol = stg_rot(l);
  const u16* aS = A   + (m0 + srow) * KA + scol;
  const u16* bS = Bs2 + (n0 + srow) * KS + scol;
  const int rrow = l & 15;
  const int ps = rd_rot(l);

  f32x4 acc[8][4] = {};

  // A: 16 units of 16 rows -> 4/wave (u = w*4+half*2+{0,1}); B: 8 units -> 2/wave
  auto STAGE_A2 = [&](int ts, int half) {
    u16* Lb = &lds[(ts % 3) * 12288];
    const int ko = (ts & 31) * 32;               // A K-wrap
    const int u0 = w * 4 + half * 2;
    gld16(aS + (size_t)u0 * 16 * KA + ko, Lb + u0 * 512);
    gld16(aS + (size_t)(u0 + 1) * 16 * KA + ko, Lb + (u0 + 1) * 512);
  };
  auto STAGE_B1 = [&](int ts, int half) {
    u16* Lb = &lds[(ts % 3) * 12288] + 8192;
    const int ko = ts * 32;                      // stacked-K, no wrap
    const int u = w * 2 + half;
    gld16(bS + (size_t)u * 16 * KS + ko, Lb + u * 512);
  };

  // prologue: steps 0,1 fully staged (6 issues each); wait -> step 0 landed
  STAGE_A2(0, 0); STAGE_A2(0, 1); STAGE_B1(0, 0); STAGE_B1(0, 1);
  STAGE_A2(1, 0); STAGE_A2(1, 1); STAGE_B1(1, 0); STAGE_B1(1, 1);
  asm volatile("s_waitcnt vmcnt(6)" ::: "memory");
  __builtin_amdgcn_sched_barrier(0);
  __builtin_amdgcn_s_barrier();

  for (int t = 0; t < NT; ++t) {
    const u16* LA = &lds[(t % 3) * 12288];
    const u16* LB = LA + 8192;
    short8 a[4], b[4];
    // ---- phase 0: read m0-3 + all b; stage half 1 of (t+2) ----
#pragma unroll
    for (int m = 0; m < 4; m++)
      a[m] = *(const short8*)&LA[(wm * 128 + m * 16 + rrow) * 32 + ps];
#pragma unroll
    for (int n = 0; n < 4; n++)
      b[n] = *(const short8*)&LB[(wn * 64 + n * 16 + rrow) * 32 + ps];
    if (t + 2 < NT) { STAGE_A2(t + 2, 0); STAGE_B1(t + 2, 0); }
    __builtin_amdgcn_sched_barrier(0);
    __builtin_amdgcn_s_barrier();
    __builtin_amdgcn_s_setprio(1);
#pragma unroll
    for (int m = 0; m < 4; m++)
#pragma unroll
      for (int n = 0; n < 4; n++)
        acc[m][n] = __builtin_amdgcn_mfma_f32_16x16x32_bf16(a[m], b[n], acc[m][n], 0, 0, 0);
    __builtin_amdgcn_s_setprio(0);
    __builtin_amdgcn_s_barrier();
    // ---- phase 1: read m4-7; stage half 2 of (t+2); counted vmcnt ----
    short8 a2[4];
#pragma unroll
    for (int m = 0; m < 4; m++)
      a2[m] = *(const short8*)&LA[(wm * 128 + (m + 4) * 16 + rrow) * 32 + ps];
    if (t + 2 < NT) {
      STAGE_A2(t + 2, 1); STAGE_B1(t + 2, 1);
      asm volatile("s_waitcnt vmcnt(6)" ::: "memory");   // stage(t+1) landed
    } else {
      asm volatile("s_waitcnt vmcnt(0)" ::: "memory");   // tail drain
    }
    __builtin_amdgcn_sched_barrier(0);
    __builtin_amdgcn_s_barrier();
    __builtin_amdgcn_s_setprio(1);
#pragma unroll
    for (int m = 0; m < 4; m++)
#pragma unroll
      for (int n = 0; n < 4; n++)
        acc[m + 4][n] = __builtin_amdgcn_mfma_f32_16x16x32_bf16(a2[m], b[n], acc[m + 4][n], 0, 0, 0);
    __builtin_amdgcn_s_setprio(0);
    __builtin_amdgcn_s_barrier();      // fences buf reuse: stage(t+3) hits buf[t%3]
  }

  const int rr = (l >> 4) * 4, cc = l & 15;
#pragma unroll
  for (int m = 0; m < 8; m++)
#pragma unroll
    for (int n = 0; n < 4; n++) {
      size_t row = m0 + wm * 128 + m * 16 + rr;
      size_t col = n0 + wn * 64 + n * 16 + cc;
#pragma unroll
      for (int j = 0; j < 4; j++)
        C[(row + j) * (size_t)N + col] = acc[m][n][j];
    }
}

// ---------- layer-0 scan: produce S0 spikes (4 elems/thread) ----------
__global__ void scan0(const float* __restrict__ Hconst,
                      float* __restrict__ syn_g, float* __restrict__ mem_g,
                      u64* __restrict__ S, int Tc) {
  int e4 = blockIdx.x * 256 + threadIdx.x;
  int e = e4 * 4;
  float4 syn = *(const float4*)&syn_g[e];
  float4 mem = *(const float4*)&mem_g[e];
  float4 hc = *(const float4*)&Hconst[e];
  for (int t = 0; t < Tc; t++) {
    bool s0 = mem.x > 1.0f, s1 = mem.y > 1.0f, s2 = mem.z > 1.0f, s3 = mem.w > 1.0f;
    u64 sp = (s0 ? 0x3F80ull : 0) | (s1 ? 0x3F800000ull : 0) |
             (s2 ? (0x3F80ull << 32) : 0) | (s3 ? (0x3F80ull << 48) : 0);
    S[(size_t)t * (NELEM / 4) + e4] = sp;
    float ns0 = AL * syn.x + hc.x, ns1 = AL * syn.y + hc.y;
    float ns2 = AL * syn.z + hc.z, ns3 = AL * syn.w + hc.w;
    float nm0 = BE * mem.x + syn.x - (s0 ? 1.0f : 0.0f);
    float nm1 = BE * mem.y + syn.y - (s1 ? 1.0f : 0.0f);
    float nm2 = BE * mem.z + syn.z - (s2 ? 1.0f : 0.0f);
    float nm3 = BE * mem.w + syn.w - (s3 ? 1.0f : 0.0f);
    syn.x = ns0; syn.y = ns1; syn.z = ns2; syn.w = ns3;
    mem.x = nm0; mem.y = nm1; mem.z = nm2; mem.w = nm3;
  }
  *(float4*)&syn_g[e] = syn;
  *(float4*)&mem_g[e] = mem;
}

// ---------- layer-1 scan, output-collapsed: z += c_u * spike ----------
__global__ void scan1z(const float* __restrict__ Hseq,
                       float* __restrict__ syn_g, float* __restrict__ mem_g,
                       float* __restrict__ z_g, int Tc, float cA0, float cB0) {
  int e4 = blockIdx.x * 256 + threadIdx.x;
  int e = e4 * 4;
  float4 syn = *(const float4*)&syn_g[e];
  float4 mem = *(const float4*)&mem_g[e];
  float4 z   = *(const float4*)&z_g[e];
  float cA = cA0, cB = cB0;
  for (int t = 0; t < Tc; t++) {
    float4 h = *(const float4*)&Hseq[(size_t)t * NELEM + e];
    float c = (cA - cB) * 20.0f;          // 1/(AL-BE) = 20
    bool s0 = mem.x > 1.0f, s1 = mem.y > 1.0f, s2 = mem.z > 1.0f, s3 = mem.w > 1.0f;
    z.x += s0 ? c : 0.0f;
    z.y += s1 ? c : 0.0f;
    z.z += s2 ? c : 0.0f;
    z.w += s3 ? c : 0.0f;
    float ns0 = AL * syn.x + h.x, ns1 = AL * syn.y + h.y;
    float ns2 = AL * syn.z + h.z, ns3 = AL * syn.w + h.w;
    float nm0 = BE * mem.x + syn.x - (s0 ? 1.0f : 0.0f);
    float nm1 = BE * mem.y + syn.y - (s1 ? 1.0f : 0.0f);
    float nm2 = BE * mem.z + syn.z - (s2 ? 1.0f : 0.0f);
    float nm3 = BE * mem.w + syn.w - (s3 ? 1.0f : 0.0f);
    syn.x = ns0; syn.y = ns1; syn.z = ns2; syn.w = ns3;
    mem.x = nm0; mem.y = nm1; mem.z = nm2; mem.w = nm3;
    cA *= (1.0f / AL); cB *= (1.0f / BE);
  }
  *(float4*)&syn_g[e] = syn;
  *(float4*)&mem_g[e] = mem;
  *(float4*)&z_g[e] = z;
}

// ---------- final: out[b][j] = sum_k z[b][k] * W2[k][j]  (fp32, tiny) ----------
__global__ __launch_bounds__(256) void zgemm(const float* __restrict__ z,
                                             const float* __restrict__ W2,
                                             float* __restrict__ out) {
  __shared__ float red[256][10];
  const int b = blockIdx.x;
  const int t = threadIdx.x;
  float local[10];
#pragma unroll
  for (int j = 0; j < 10; j++) local[j] = 0.f;
  for (int k = t; k < D_H; k += 256) {
    float zv = z[(size_t)b * D_H + k];
    const float* wrow = &W2[(size_t)k * D_OUT];
#pragma unroll
    for (int j = 0; j < 10; j++) local[j] += zv * wrow[j];
  }
#pragma unroll
  for (int j = 0; j < 10; j++) red[t][j] = local[j];
  __syncthreads();
  for (int s = 128; s > 0; s >>= 1) {
    if (t < s)
#pragma unroll
      for (int j = 0; j < 10; j++) red[t][j] += red[t + s][j];
    __syncthreads();
  }
  if (t < 10) out[b * D_OUT + t] = red[0][t];
}

__global__ void diag(float* out, float v) {
  if (threadIdx.x == 0 && blockIdx.x == 0) out[0] = v;
}

extern "C" void kernel_launch(void* const* d_in, const int* in_sizes, int n_in,
                              void* d_out, int out_size, void* d_ws, size_t ws_size,
                              hipStream_t stream) {
  (void)in_sizes; (void)n_in; (void)out_size;
  const float* inp = (const float*)d_in[0];
  const float* W0  = (const float*)d_in[1];
  const float* W1  = (const float*)d_in[2];
  const float* W2  = (const float*)d_in[3];
  float* out = (float*)d_out;

  uint8_t* base = (uint8_t*)d_ws;
  size_t off = 0;
  auto alloc = [&](size_t bytes) -> void* {
    void* r = base + off;
    off += (bytes + 255) & ~(size_t)255;
    return r;
  };

  float* H0   = (float*)alloc((size_t)NELEM * 4);
  float* syn0 = (float*)alloc((size_t)NELEM * 4);   // states+z contiguous -> one memset
  float* mem0 = (float*)alloc((size_t)NELEM * 4);
  float* syn1 = (float*)alloc((size_t)NELEM * 4);
  float* mem1 = (float*)alloc((size_t)NELEM * 4);
  float* zbuf = (float*)alloc((size_t)NELEM * 4);
  u16* W1s = (u16*)alloc((size_t)D_H * 2048 * 2);
  size_t fixedEnd = off;

  int Tc = 0;
  const int cand[7] = {50, 25, 20, 10, 5, 4, 2};
  for (int i = 0; i < 7; i++) {
    // per-chunk: S0c (2B/elem/step) + H1c (4B/elem/step); A0/BT0 aliased inside
    size_t per = (size_t)cand[i] * ((size_t)NELEM * 2 + (size_t)NELEM * 4);
    if (fixedEnd + per + 16 * 256 <= ws_size) { Tc = cand[i]; break; }
  }
  if (Tc == 0) {
    diag<<<1, 1, 0, stream>>>(out, (float)ws_size);
    return;
  }
  u16*   S0c = (u16*)alloc((size_t)Tc * NELEM * 2);
  float* H1c = (float*)alloc((size_t)Tc * NELEM * 4);
  // A0/BT0 live only during the prologue (before any S0c/H1c write) -> alias
  u16* A0  = (u16*)S0c;                       // 4.69 MB
  u16* BT0 = A0 + (size_t)BDIM * K0TOT;       // 4.69 MB  (Tc>=2 => region fits)

  // zero all states + z (contiguous)
  hipMemsetAsync(syn0, 0, (size_t)5 * NELEM * 4, stream);

  prep0<<<dim3(10, BDIM), 256, 0, stream>>>(inp, W0, A0, BT0);
  prep1s<<<dim3(8, D_H), 256, 0, stream>>>(W1, W1s);

  // H0 = A0 @ BT0^T : M=1024, N=1024, K=2400 (bf16x2-split fp32-grade)
  gemm_bt_t<K0TOT><<<dim3(8 * 8), 256, 0, stream>>>(A0, BT0, H0);

  const int nc = TSTEPS / Tc;
  for (int c = 0; c < nc; c++) {
    const int tbase = c * Tc;
    const float cA0 = (float)pow(0.9, (double)(TSTEPS - 1 - tbase));
    const float cB0 = (float)pow(0.85, (double)(TSTEPS - 1 - tbase));
    scan0<<<dim3(NELEM / 1024), 256, 0, stream>>>(H0, syn0, mem0, (u64*)S0c, Tc);
    // H1 = S0 @ W1s (stacked hi;lo, A k-wrap): 256x128 blocks, phase-interleaved
    gemm_dual5<<<dim3(Tc * 32), 256, 0, stream>>>(S0c, W1s, H1c);
    scan1z<<<dim3(NELEM / 1024), 256, 0, stream>>>(H1c, syn1, mem1, zbuf, Tc, cA0, cB0);
  }
  zgemm<<<dim3(BDIM), 256, 0, stream>>>(zbuf, W2, out);
}

// Round 13
// 534.363 us; speedup vs baseline: 1.1994x; 1.1994x over previous
//
#include <hip/hip_runtime.h>
#include <hip/hip_bf16.h>
#include <stdint.h>
#include <math.h>

typedef unsigned short u16;
typedef unsigned int u32;
typedef unsigned long long u64;
typedef __attribute__((ext_vector_type(8))) short short8;
typedef __attribute__((ext_vector_type(4))) float f32x4;

static constexpr int BDIM  = 1024;   // batch
static constexpr int D_IN  = 784;
static constexpr int D_H   = 1024;
static constexpr int D_OUT = 10;
static constexpr int TSTEPS = 100;
static constexpr int K0SEG = 800;    // 784 padded to 800 (25*32)
static constexpr int K0TOT = 2400;   // 3 segments: ihi*whi + ihi*wlo + ilo*whi
static constexpr int NELEM = 1024 * 1024;

#define AL 0.9f
#define BE 0.85f

// ---------- helpers ----------
__device__ __forceinline__ void gld16(const void* g, void* l) {
  __builtin_amdgcn_global_load_lds(
      (const __attribute__((address_space(1))) u32*)g,
      (__attribute__((address_space(3))) u32*)l, 16, 0, 0);
}
__device__ __forceinline__ u16 f2bf(float v) {
  __hip_bfloat16 h = __float2bfloat16(v);
  u16 r; __builtin_memcpy(&r, &h, 2); return r;
}
__device__ __forceinline__ float bf2f(u16 b) {
  __hip_bfloat16 h; __builtin_memcpy(&h, &b, 2); return __bfloat162float(h);
}

// LDS bank-derotation (round-5, verified: SQ_LDS_BANK_CONFLICT -> 0):
// store: LDS[r][p] holds global 16B-slot c = (p - (r>>1)) & 3 of row r.
// Invariant across 16-row strips (strip stride 16 -> (r>>1) stride 8 == 0 mod 4).
__device__ __forceinline__ int stg_rot(int l) { return (((l & 3) - (l >> 3)) & 3) << 3; }
__device__ __forceinline__ int rd_rot(int l) {
  return (((l >> 4) + ((l & 15) >> 1)) & 3) << 3;
}

// ---------- prep: build bf16 hi/lo operand matrices ----------
__global__ void prep0(const float* __restrict__ inp, const float* __restrict__ W0,
                      u16* __restrict__ A0, u16* __restrict__ BT0) {
  int kp = blockIdx.x * 256 + threadIdx.x;
  if (kp >= K0TOT) return;
  int row = blockIdx.y;
  int seg = kp / K0SEG;
  int kk  = kp - seg * K0SEG;
  float av = (kk < D_IN) ? inp[row * D_IN + kk] : 0.f;
  u16 ahi = f2bf(av);
  u16 alo = f2bf(av - bf2f(ahi));
  A0[(size_t)row * K0TOT + kp] = (seg < 2) ? ahi : alo;
  float wv = (kk < D_IN) ? W0[kk * D_H + row] : 0.f;
  u16 whi = f2bf(wv);
  u16 wlo = f2bf(wv - bf2f(whi));
  BT0[(size_t)row * K0TOT + kp] = (seg == 0) ? whi : ((seg == 1) ? wlo : whi);
}

__global__ void prep1(const float* __restrict__ W1, u16* __restrict__ W1h,
                      u16* __restrict__ W1l) {
  int k = blockIdx.x * 256 + threadIdx.x;
  int n = blockIdx.y;
  float v = W1[(size_t)k * D_H + n];
  u16 hi = f2bf(v);
  W1h[(size_t)n * D_H + k] = hi;
  W1l[(size_t)n * D_H + k] = f2bf(v - bf2f(hi));
}

// ---------- H0 GEMM (one-time): 64x64 tiles -> 256 blocks, depth-5 pipeline ----
// Each block: 4 waves (2x2) of 32x32. LDS 5 bufs x (A 4KB | B 4KB) = 40KB.
// Per-wave 2 issues/stage; prologue 4 stages = 8 outstanding, vmcnt(6) => stage
// t+1 landed each step. Same K accumulation order as before -> bit-identical H0.
template <int KTOT>
__global__ __launch_bounds__(256) void gemm_bt64(
    const u16* __restrict__ A, const u16* __restrict__ BT, float* __restrict__ C) {
  constexpr int N = 1024, NT = KTOT / 32;       // 75 K-steps
  constexpr int BUF = 4096;                      // u16 per buffer (8KB)
  __shared__ u16 lds[5 * BUF];
  const int nwg = gridDim.x;
  const int bid = blockIdx.x;
  const int wg = (bid & 7) * (nwg >> 3) + (bid >> 3);   // 256 % 8 == 0
  const int bm = wg >> 4, bn = wg & 15;          // 16x16 tile grid
  const int tid = threadIdx.x;
  const int w = tid >> 6, l = tid & 63;
  const int wm = w >> 1, wn = w & 1;             // 2x2 waves of 32x32
  const size_t m0 = (size_t)bm * 64, n0 = (size_t)bn * 64;

  const int srow = l >> 2;
  const int scol = stg_rot(l);
  const u16* aS = A  + (m0 + w * 16 + srow) * KTOT + scol;
  const u16* bS = BT + (n0 + w * 16 + srow) * KTOT + scol;
  const int dd = w * 512;

  const int rrow = l & 15;
  const int ps = rd_rot(l);

  f32x4 acc[2][2] = {};

  auto STAGE = [&](int ts) {
    u16* Lb = &lds[(ts % 5) * BUF];
    const int ko = ts * 32;
    gld16(aS + ko, Lb + dd);
    gld16(bS + ko, Lb + 2048 + dd);
  };

  STAGE(0); STAGE(1); STAGE(2); STAGE(3);
  asm volatile("s_waitcnt vmcnt(6)" ::: "memory");
  __builtin_amdgcn_sched_barrier(0);
  __builtin_amdgcn_s_barrier();

  for (int t = 0; t < NT; ++t) {
    const u16* LA = &lds[(t % 5) * BUF];
    const u16* LB = LA + 2048;
    short8 a[2], b[2];
#pragma unroll
    for (int m = 0; m < 2; m++)
      a[m] = *(const short8*)&LA[(wm * 32 + m * 16 + rrow) * 32 + ps];
#pragma unroll
    for (int n = 0; n < 2; n++)
      b[n] = *(const short8*)&LB[(wn * 32 + n * 16 + rrow) * 32 + ps];
    if (t + 4 < NT) {
      STAGE(t + 4);   // writes buf[(t-1)%5]; its reads done before t-1's barrier
      asm volatile("s_waitcnt vmcnt(6)" ::: "memory");
    } else {
      asm volatile("s_waitcnt vmcnt(0)" ::: "memory");
    }
    __builtin_amdgcn_sched_barrier(0);
    __builtin_amdgcn_s_barrier();
#pragma unroll
    for (int m = 0; m < 2; m++)
#pragma unroll
      for (int n = 0; n < 2; n++)
        acc[m][n] = __builtin_amdgcn_mfma_f32_16x16x32_bf16(a[m], b[n], acc[m][n], 0, 0, 0);
    __builtin_amdgcn_s_barrier();
  }

  const int rr = (l >> 4) * 4, cc = l & 15;
#pragma unroll
  for (int m = 0; m < 2; m++)
#pragma unroll
    for (int n = 0; n < 2; n++) {
      size_t row = m0 + wm * 32 + m * 16 + rr;
      size_t col = n0 + wn * 32 + n * 16 + cc;
#pragma unroll
      for (int j = 0; j < 4; j++)
        C[(row + j) * (size_t)N + col] = acc[m][n][j];
    }
}

// ---------- layer-1 GEMM (round-5 dual2, verified best: 4.3 us/step) ----------
// 128x128 block, 64x64/wave, BK=32, 3-deep counted-vmcnt(6) pipeline,
// 72KB LDS -> 2 blocks/CU (cross-block overlap fills barrier gaps).
__global__ __launch_bounds__(256) void gemm_dual2(
    const u16* __restrict__ A, const u16* __restrict__ Bh, const u16* __restrict__ Bl,
    float* __restrict__ C) {
  constexpr int N = 1024, K = 1024, NT = K / 32;
  __shared__ u16 lds[3 * 12288];
  const int nwg = gridDim.x;
  const int bid = blockIdx.x;
  const int wg = (bid & 7) * (nwg >> 3) + (bid >> 3);   // bijective: nwg % 8 == 0
  const int bm = wg >> 3, bn = wg & 7;
  const int tid = threadIdx.x;
  const int w = tid >> 6, l = tid & 63;
  const int wm = w >> 1, wn = w & 1;
  const size_t m0 = (size_t)bm * 128, n0 = (size_t)bn * 128;

  const int srow0 = (w * 2 + 0) * 16 + (l >> 2);
  const int srow1 = (w * 2 + 1) * 16 + (l >> 2);
  const int scol  = stg_rot(l);
  const u16* aS0 = A  + (m0 + srow0) * K + scol;
  const u16* aS1 = A  + (m0 + srow1) * K + scol;
  const u16* hS0 = Bh + (n0 + srow0) * K + scol;
  const u16* hS1 = Bh + (n0 + srow1) * K + scol;
  const u16* lS0 = Bl + (n0 + srow0) * K + scol;
  const u16* lS1 = Bl + (n0 + srow1) * K + scol;
  const int d0 = (w * 2 + 0) * 512;
  const int d1 = (w * 2 + 1) * 512;

  const int rrow = l & 15;
  const int ps = rd_rot(l);

  f32x4 acc[4][4] = {};

  auto STAGE = [&](int ts) {
    u16* Lb = &lds[(ts % 3) * 12288];
    const int ko = ts * 32;
    gld16(aS0 + ko, Lb + d0);
    gld16(aS1 + ko, Lb + d1);
    gld16(hS0 + ko, Lb + 4096 + d0);
    gld16(hS1 + ko, Lb + 4096 + d1);
    gld16(lS0 + ko, Lb + 8192 + d0);
    gld16(lS1 + ko, Lb + 8192 + d1);
  };

  STAGE(0);
  STAGE(1);
  asm volatile("s_waitcnt vmcnt(6)" ::: "memory");
  __builtin_amdgcn_sched_barrier(0);
  __builtin_amdgcn_s_barrier();

  for (int t = 0; t < NT; ++t) {
    const u16* Lb = &lds[(t % 3) * 12288];
    short8 a[4], bh[4], bl[4];
#pragma unroll
    for (int m = 0; m < 4; m++)
      a[m] = *(const short8*)&Lb[(wm * 64 + m * 16 + rrow) * 32 + ps];
#pragma unroll
    for (int n = 0; n < 4; n++) {
      bh[n] = *(const short8*)&Lb[4096 + (wn * 64 + n * 16 + rrow) * 32 + ps];
      bl[n] = *(const short8*)&Lb[8192 + (wn * 64 + n * 16 + rrow) * 32 + ps];
    }
    if (t + 2 < NT) {
      STAGE(t + 2);
      asm volatile("s_waitcnt vmcnt(6)" ::: "memory");
    } else {
      asm volatile("s_waitcnt vmcnt(0)" ::: "memory");
    }
    __builtin_amdgcn_sched_barrier(0);
    __builtin_amdgcn_s_barrier();
    __builtin_amdgcn_s_setprio(1);
#pragma unroll
    for (int m = 0; m < 4; m++)
#pragma unroll
      for (int n = 0; n < 4; n++)
        acc[m][n] = __builtin_amdgcn_mfma_f32_16x16x32_bf16(a[m], bh[n], acc[m][n], 0, 0, 0);
#pragma unroll
    for (int m = 0; m < 4; m++)
#pragma unroll
      for (int n = 0; n < 4; n++)
        acc[m][n] = __builtin_amdgcn_mfma_f32_16x16x32_bf16(a[m], bl[n], acc[m][n], 0, 0, 0);
    __builtin_amdgcn_s_setprio(0);
    __builtin_amdgcn_s_barrier();
  }

  const int rr = (l >> 4) * 4, cc = l & 15;
#pragma unroll
  for (int m = 0; m < 4; m++)
#pragma unroll
    for (int n = 0; n < 4; n++) {
      size_t row = m0 + wm * 64 + m * 16 + rr;
      size_t col = n0 + wn * 64 + n * 16 + cc;
#pragma unroll
      for (int j = 0; j < 4; j++)
        C[(row + j) * (size_t)N + col] = acc[m][n][j];
    }
}

// ---------- scan bodies (4 elems/thread) ----------
__device__ __forceinline__ void scan0_body(
    int e4, const float* __restrict__ Hconst, float* __restrict__ syn_g,
    float* __restrict__ mem_g, u64* __restrict__ S, int Tc) {
  int e = e4 * 4;
  float4 syn = *(const float4*)&syn_g[e];
  float4 mem = *(const float4*)&mem_g[e];
  float4 hc = *(const float4*)&Hconst[e];
  for (int t = 0; t < Tc; t++) {
    bool s0 = mem.x > 1.0f, s1 = mem.y > 1.0f, s2 = mem.z > 1.0f, s3 = mem.w > 1.0f;
    u64 sp = (s0 ? 0x3F80ull : 0) | (s1 ? 0x3F800000ull : 0) |
             (s2 ? (0x3F80ull << 32) : 0) | (s3 ? (0x3F80ull << 48) : 0);
    S[(size_t)t * (NELEM / 4) + e4] = sp;
    float ns0 = AL * syn.x + hc.x, ns1 = AL * syn.y + hc.y;
    float ns2 = AL * syn.z + hc.z, ns3 = AL * syn.w + hc.w;
    float nm0 = BE * mem.x + syn.x - (s0 ? 1.0f : 0.0f);
    float nm1 = BE * mem.y + syn.y - (s1 ? 1.0f : 0.0f);
    float nm2 = BE * mem.z + syn.z - (s2 ? 1.0f : 0.0f);
    float nm3 = BE * mem.w + syn.w - (s3 ? 1.0f : 0.0f);
    syn.x = ns0; syn.y = ns1; syn.z = ns2; syn.w = ns3;
    mem.x = nm0; mem.y = nm1; mem.z = nm2; mem.w = nm3;
  }
  *(float4*)&syn_g[e] = syn;
  *(float4*)&mem_g[e] = mem;
}

__device__ __forceinline__ void scan1z_body(
    int e4, const float* __restrict__ Hseq, float* __restrict__ syn_g,
    float* __restrict__ mem_g, float* __restrict__ z_g, int Tc,
    float cA0, float cB0) {
  int e = e4 * 4;
  float4 syn = *(const float4*)&syn_g[e];
  float4 mem = *(const float4*)&mem_g[e];
  float4 z   = *(const float4*)&z_g[e];
  float cA = cA0, cB = cB0;
  for (int t = 0; t < Tc; t++) {
    float4 h = *(const float4*)&Hseq[(size_t)t * NELEM + e];
    float c = (cA - cB) * 20.0f;          // 1/(AL-BE) = 20
    bool s0 = mem.x > 1.0f, s1 = mem.y > 1.0f, s2 = mem.z > 1.0f, s3 = mem.w > 1.0f;
    z.x += s0 ? c : 0.0f;
    z.y += s1 ? c : 0.0f;
    z.z += s2 ? c : 0.0f;
    z.w += s3 ? c : 0.0f;
    float ns0 = AL * syn.x + h.x, ns1 = AL * syn.y + h.y;
    float ns2 = AL * syn.z + h.z, ns3 = AL * syn.w + h.w;
    float nm0 = BE * mem.x + syn.x - (s0 ? 1.0f : 0.0f);
    float nm1 = BE * mem.y + syn.y - (s1 ? 1.0f : 0.0f);
    float nm2 = BE * mem.z + syn.z - (s2 ? 1.0f : 0.0f);
    float nm3 = BE * mem.w + syn.w - (s3 ? 1.0f : 0.0f);
    syn.x = ns0; syn.y = ns1; syn.z = ns2; syn.w = ns3;
    mem.x = nm0; mem.y = nm1; mem.z = nm2; mem.w = nm3;
    cA *= (1.0f / AL); cB *= (1.0f / BE);
  }
  *(float4*)&syn_g[e] = syn;
  *(float4*)&mem_g[e] = mem;
  *(float4*)&z_g[e] = z;
}

// prologue scan0 (chunk 0)
__global__ void scan0k(const float* __restrict__ Hconst, float* __restrict__ syn_g,
                       float* __restrict__ mem_g, u64* __restrict__ S, int Tc) {
  scan0_body(blockIdx.x * 256 + threadIdx.x, Hconst, syn_g, mem_g, S, Tc);
}

// fused: blocks [0,1024) = scan1z(chunk c); blocks [1024,2048) = scan0(chunk c+1)
__global__ void scanF(const float* __restrict__ H1c, float* __restrict__ syn1,
                      float* __restrict__ mem1, float* __restrict__ z_g,
                      int csC, float cA0, float cB0,
                      const float* __restrict__ H0, float* __restrict__ syn0,
                      float* __restrict__ mem0, u64* __restrict__ S0c, int csN) {
  int b = blockIdx.x;
  if (b < 1024) {
    scan1z_body(b * 256 + threadIdx.x, H1c, syn1, mem1, z_g, csC, cA0, cB0);
  } else {
    scan0_body((b - 1024) * 256 + threadIdx.x, H0, syn0, mem0, S0c, csN);
  }
}

// ---------- final: out[b][j] = sum_k z[b][k] * W2[k][j]  (fp32, tiny) ----------
__global__ __launch_bounds__(256) void zgemm(const float* __restrict__ z,
                                             const float* __restrict__ W2,
                                             float* __restrict__ out) {
  __shared__ float red[256][10];
  const int b = blockIdx.x;
  const int t = threadIdx.x;
  float local[10];
#pragma unroll
  for (int j = 0; j < 10; j++) local[j] = 0.f;
  for (int k = t; k < D_H; k += 256) {
    float zv = z[(size_t)b * D_H + k];
    const float* wrow = &W2[(size_t)k * D_OUT];
#pragma unroll
    for (int j = 0; j < 10; j++) local[j] += zv * wrow[j];
  }
#pragma unroll
  for (int j = 0; j < 10; j++) red[t][j] = local[j];
  __syncthreads();
  for (int s = 128; s > 0; s >>= 1) {
    if (t < s)
#pragma unroll
      for (int j = 0; j < 10; j++) red[t][j] += red[t + s][j];
    __syncthreads();
  }
  if (t < 10) out[b * D_OUT + t] = red[0][t];
}

__global__ void diag(float* out, float v) {
  if (threadIdx.x == 0 && blockIdx.x == 0) out[0] = v;
}

extern "C" void kernel_launch(void* const* d_in, const int* in_sizes, int n_in,
                              void* d_out, int out_size, void* d_ws, size_t ws_size,
                              hipStream_t stream) {
  (void)in_sizes; (void)n_in; (void)out_size;
  const float* inp = (const float*)d_in[0];
  const float* W0  = (const float*)d_in[1];
  const float* W1  = (const float*)d_in[2];
  const float* W2  = (const float*)d_in[3];
  float* out = (float*)d_out;

  uint8_t* base = (uint8_t*)d_ws;
  size_t off = 0;
  auto alloc = [&](size_t bytes) -> void* {
    void* r = base + off;
    off += (bytes + 255) & ~(size_t)255;
    return r;
  };

  float* H0   = (float*)alloc((size_t)NELEM * 4);
  float* syn0 = (float*)alloc((size_t)NELEM * 4);   // states+z contiguous -> one memset
  float* mem0 = (float*)alloc((size_t)NELEM * 4);
  float* syn1 = (float*)alloc((size_t)NELEM * 4);
  float* mem1 = (float*)alloc((size_t)NELEM * 4);
  float* zbuf = (float*)alloc((size_t)NELEM * 4);
  u16* W1h = (u16*)alloc((size_t)D_H * D_H * 2);
  u16* W1l = (u16*)alloc((size_t)D_H * D_H * 2);
  size_t fixedEnd = off;

  int Tc = 0;
  const int cand[7] = {50, 34, 25, 20, 10, 5, 4};
  for (int i = 0; i < 7; i++) {
    size_t per = (size_t)cand[i] * ((size_t)NELEM * 2 + (size_t)NELEM * 4);
    if (fixedEnd + per + 16 * 256 <= ws_size) { Tc = cand[i]; break; }
  }
  if (Tc == 0) {
    diag<<<1, 1, 0, stream>>>(out, (float)ws_size);
    return;
  }
  u16*   S0c = (u16*)alloc((size_t)Tc * NELEM * 2);
  float* H1c = (float*)alloc((size_t)Tc * NELEM * 4);
  // A0/BT0 live only during the prologue (before any S0c/H1c write) -> alias.
  // 9.83 MB total; S0c+H1c region >= 24 MB for Tc >= 4.
  u16* A0  = (u16*)S0c;
  u16* BT0 = A0 + (size_t)BDIM * K0TOT;

  // zero all states + z (contiguous)
  hipMemsetAsync(syn0, 0, (size_t)5 * NELEM * 4, stream);

  prep0<<<dim3(10, BDIM), 256, 0, stream>>>(inp, W0, A0, BT0);
  prep1<<<dim3(4, D_H), 256, 0, stream>>>(W1, W1h, W1l);

  // H0 = A0 @ BT0^T : M=1024, N=1024, K=2400 (bf16x2-split fp32-grade)
  gemm_bt64<K0TOT><<<dim3(256), 256, 0, stream>>>(A0, BT0, H0);

  int done = 0;
  const int cs0 = (TSTEPS < Tc) ? TSTEPS : Tc;
  scan0k<<<dim3(NELEM / 1024), 256, 0, stream>>>(H0, syn0, mem0, (u64*)S0c, cs0);
  while (done < TSTEPS) {
    int csC = TSTEPS - done < Tc ? TSTEPS - done : Tc;
    int rem = TSTEPS - done - csC;
    int csN = rem < Tc ? rem : Tc;
    const float cA0 = (float)pow(0.9, (double)(TSTEPS - 1 - done));
    const float cB0 = (float)pow(0.85, (double)(TSTEPS - 1 - done));
    gemm_dual2<<<dim3(csC * 64), 256, 0, stream>>>(S0c, W1h, W1l, H1c);
    scanF<<<dim3(csN > 0 ? 2048 : 1024), 256, 0, stream>>>(
        H1c, syn1, mem1, zbuf, csC, cA0, cB0, H0, syn0, mem0, (u64*)S0c, csN);
    done += csC;
  }
  zgemm<<<dim3(BDIM), 256, 0, stream>>>(zbuf, W2, out);
}